// Round 2
// baseline (40.484 us; speedup 1.0000x reference)
//
#include <hip/hip_runtime.h>
#include <math.h>

// B=256, C=500, D=256. wf layout [C][B][D] -> row (c,b) is 1KB contiguous.
// Block blk: c = blk>>2, b in [ (blk&3)*64, +64 ) -> 64 contiguous rows = 64KB
// contiguous global memory. 4 waves x 16 rows each, depth-2 float4 pipeline.
#define BB 256
#define CC 500
#define DD 256
#define MARGIN 0.3f

__global__ __launch_bounds__(256) void fused_loss_kernel(
    const float* __restrict__ logits,   // [B, C]
    const float* __restrict__ wf,       // [C, B, D]
    const int*   __restrict__ labels,   // [B, C]
    float*       __restrict__ out)      // [B]
{
    const int blk  = blockIdx.x;        // [0, 2000)
    const int c    = blk >> 2;          // [0, 500)
    const int b0   = (blk & 3) << 6;    // 0, 64, 128, 192
    const int tid  = threadIdx.x;
    const int w    = tid >> 6;          // wave id 0..3
    const int lane = tid & 63;

    __shared__ float partial[64];       // per-row (b) partial: bce + rejection
    __shared__ int   flag[64];          // label==0 per row

    // Issue the streaming loads ASAP: wave w owns rows b0+w*16 .. +16,
    // 16 contiguous 1KB rows. Each lane reads float4 -> 1KB/wave/row coalesced.
    const float* base = wf + (((size_t)c * BB) + b0 + (w << 4)) * DD + (lane << 2);
    float4 v0 = *reinterpret_cast<const float4*>(base);
    float4 v1 = *reinterpret_cast<const float4*>(base + DD);

    // Per-(b,c) BCE element + label flag, loaded once per block (64 pairs).
    if (tid < 64) {
        const int   b   = b0 + tid;
        const int   lab = labels[b * CC + c];
        const float x   = logits[b * CC + c];
        const float y   = (float)lab;
        // stable BCE: max(x,0) - x*y + log1p(exp(-|x|))
        partial[tid] = fmaxf(x, 0.0f) - x * y + log1pf(__expf(-fabsf(x)));
        flag[tid]    = (lab == 0);
    }
    __syncthreads();

    #pragma unroll
    for (int i = 0; i < 16; ++i) {
        float4 cur = v0;
        v0 = v1;
        if (i + 2 < 16)
            v1 = *reinterpret_cast<const float4*>(base + (size_t)(i + 2) * DD);
        float m = fmaxf(fmaxf(cur.x, cur.y), fmaxf(cur.z, cur.w));
        #pragma unroll
        for (int off = 32; off > 0; off >>= 1)
            m = fmaxf(m, __shfl_xor(m, off));
        if (lane == 0 && flag[(w << 4) + i]) {
            const float s = 1.0f / (1.0f + __expf(-m));   // sigmoid(row max)
            partial[(w << 4) + i] += fmaxf(s - MARGIN, 0.0f);  // single writer
        }
    }
    __syncthreads();

    // One fire-and-forget atomic per row; 64-wide, coalesced address range.
    if (tid < 64)
        atomicAdd(&out[b0 + tid], partial[tid]);
}

extern "C" void kernel_launch(void* const* d_in, const int* in_sizes, int n_in,
                              void* d_out, int out_size, void* d_ws, size_t ws_size,
                              hipStream_t stream) {
    const float* logits = (const float*)d_in[0];
    const float* wf     = (const float*)d_in[1];
    const int*   labels = (const int*)d_in[2];
    float*       out    = (float*)d_out;

    hipMemsetAsync(out, 0, out_size * sizeof(float), stream);

    dim3 grid(2000);   // 500 c * 4 b-quarters; <=8 blocks/CU -> single pass
    dim3 block(256);
    fused_loss_kernel<<<grid, block, 0, stream>>>(logits, wf, labels, out);
}

// Round 3
// 29.133 us; speedup vs baseline: 1.3896x; 1.3896x over previous
//
#include <hip/hip_runtime.h>
#include <math.h>

// B=256, C=500, D=256. wf layout [C][B][D]: row (c,b) = 1KB contiguous.
// One block per sample b (grid=256 -> exactly 1 block/CU, single pass).
// 16 waves; wave w handles rows c = w, w+16, ... with next-row prefetch.
// No memset, no atomics: block computes out[b] completely, one store.
#define BB 256
#define CC 500
#define DD 256
#define MARGIN 0.3f

__global__ __launch_bounds__(1024) void fused_loss_kernel(
    const float* __restrict__ logits,   // [B, C]
    const float* __restrict__ wf,       // [C, B, D]
    const int*   __restrict__ labels,   // [B, C]
    float*       __restrict__ out)      // [B]
{
    const int b    = blockIdx.x;
    const int tid  = threadIdx.x;
    const int w    = tid >> 6;          // wave 0..15
    const int lane = tid & 63;

    __shared__ float sflag[CC];         // 1.0f if label==0 else 0.0f
    __shared__ float wsum[16];

    float acc = 0.0f;

    // ---- BCE + label flags: one coalesced pass over this sample's row ----
    if (tid < CC) {
        const int   lab = labels[b * CC + tid];
        const float x   = logits[b * CC + tid];
        sflag[tid] = (lab == 0) ? 1.0f : 0.0f;
        const float y = (float)lab;
        // stable BCE: max(x,0) - x*y + log1p(exp(-|x|))
        acc = fmaxf(x, 0.0f) - x * y + log1pf(__expf(-fabsf(x)));
    }
    __syncthreads();

    // ---- rejection: stream rows c = w, w+16, ... (1KB per row per wave) ----
    {
        const size_t step = (size_t)16 * BB * DD;                  // 16 c's ahead
        const float* p = wf + ((size_t)w * BB + b) * DD + (lane << 2);
        float4 v0, v1;
        if (w < CC) v0 = *reinterpret_cast<const float4*>(p);      // always true
        for (int c = w; c < CC; c += 16) {
            if (c + 16 < CC)
                v1 = *reinterpret_cast<const float4*>(p + step);   // prefetch
            p += step;
            float m = fmaxf(fmaxf(v0.x, v0.y), fmaxf(v0.z, v0.w));
            #pragma unroll
            for (int off = 32; off > 0; off >>= 1)
                m = fmaxf(m, __shfl_xor(m, off));
            if (lane == 0) {
                const float s = 1.0f / (1.0f + __expf(-m));        // sigmoid(max)
                acc += sflag[c] * fmaxf(s - MARGIN, 0.0f);
            }
            v0 = v1;
        }
    }

    // ---- block reduce: wave reduce -> LDS -> wave-0 reduce -> single store ----
    #pragma unroll
    for (int off = 32; off > 0; off >>= 1)
        acc += __shfl_xor(acc, off);
    if (lane == 0) wsum[w] = acc;
    __syncthreads();
    if (tid < 64) {
        float v = (tid < 16) ? wsum[tid] : 0.0f;
        #pragma unroll
        for (int off = 8; off > 0; off >>= 1)
            v += __shfl_xor(v, off);
        if (tid == 0) out[b] = v;
    }
}

extern "C" void kernel_launch(void* const* d_in, const int* in_sizes, int n_in,
                              void* d_out, int out_size, void* d_ws, size_t ws_size,
                              hipStream_t stream) {
    const float* logits = (const float*)d_in[0];
    const float* wf     = (const float*)d_in[1];
    const int*   labels = (const int*)d_in[2];
    float*       out    = (float*)d_out;

    fused_loss_kernel<<<dim3(BB), dim3(1024), 0, stream>>>(logits, wf, labels, out);
}